// Round 5
// baseline (107.097 us; speedup 1.0000x reference)
//
#include <hip/hip_runtime.h>
#include <stdint.h>

// NFP pooling: out[b,o,i,j] = -sum_c |x[b,c,i+1,j+1] - x[b,c,i+di,j+dj]|
// x: (8,128,224,224) f32 -> out: (8,8,222,222) f32.
//
// R5: LDS-staged. Block = 4 output rows x 222 cols, channel loop inside.
// Per channel: async global_load_lds of 6 contiguous input rows (5376 B),
// double-buffered; each thread computes 4 cols x 2 rows from LDS via
// ds_read_b128. Cuts L1-miss-path traffic 616->307 MB and decouples
// memory latency from VGPR ILP (R2-R4 evidence: latency/miss-queue bound).

constexpr int C = 128;
constexpr int H = 224;
constexpr int W = 224;
constexpr int HO = 222;
constexpr int WO = 222;
constexpr int PLANE = H * W;              // 50176
constexpr int OPLANE = HO * WO;           // 49284
constexpr uint32_t TOTF = 8u * C * PLANE; // 51,380,224 floats in x
constexpr int TILES = 56;                 // row-tiles per batch (4 rows, last 2)
constexpr int NBLK = 8 * TILES;           // 448 blocks
constexpr int BUF_F = 1600;               // 6*224=1344 used, 1536 staged, pad for b128 overread

__device__ __forceinline__ void gload16(const float* g, float* l) {
    __builtin_amdgcn_global_load_lds(
        (const __attribute__((address_space(1))) void*)g,
        (__attribute__((address_space(3))) void*)l, 16, 0, 0);
}

// stage 6 rows (6 slots x 1024 B) of one channel plane into buf.
// coff = float offset of (batch,c) plane start + i0*W. LDS dest base is
// wave-uniform (HW scatters lane*16); global source is per-lane, clamped.
__device__ __forceinline__ void stage(const float* __restrict__ x, uint32_t coff,
                                      float* buf, int wv, int lane) {
#pragma unroll
    for (int s = 0; s < 3; ++s) {
        int slot = wv + 2 * s;            // wave0: 0,2,4  wave1: 1,3,5
        uint32_t fi = coff + slot * 256 + lane * 4;
        if (fi > TOTF - 4) fi = TOTF - 4; // clamp (last tile of last plane)
        gload16(x + fi, buf + slot * 256);
    }
}

__global__ __launch_bounds__(128, 1)
void nfp_sad_kernel(const float* __restrict__ x, float* __restrict__ out) {
    __shared__ float lds_buf[2][BUF_F];   // 12.8 KB

    int bid = blockIdx.x;
    int batch = bid / TILES;
    int tile = bid % TILES;
    int i0 = tile * 4;                    // first output row of tile

    int wv = threadIdx.x >> 6;            // 0..1
    int lane = threadIdx.x & 63;
    int g = lane;                         // col group: cols 4g..4g+3 (g<56 active)
    int cg = 4 * g;
    int rb = 2 * wv;                      // buffer row base for this thread

    float acc0[8][4], acc1[8][4];
#pragma unroll
    for (int o = 0; o < 8; ++o)
#pragma unroll
        for (int q = 0; q < 4; ++q) { acc0[o][q] = 0.0f; acc1[o][q] = 0.0f; }

    uint32_t coff = (uint32_t)(batch * C) * PLANE + (uint32_t)i0 * W;
    stage(x, coff, &lds_buf[0][0], wv, lane);
    uint32_t cnext = coff + PLANE;
    __syncthreads();

    for (int c = 0; c < C; ++c) {
        if (c + 1 < C) {                  // issue next-channel DMA before compute
            stage(x, cnext, &lds_buf[(c + 1) & 1][0], wv, lane);
            cnext += PLANE;
        }

        if (lane < 56) {
            const float* lb = &lds_buf[c & 1][0];
            float v[4][8];
#pragma unroll
            for (int k = 0; k < 4; ++k) {
                float4 A = *(const float4*)(lb + (rb + k) * W + cg);
                float4 Bv = *(const float4*)(lb + (rb + k) * W + cg + 4);
                v[k][0] = A.x; v[k][1] = A.y; v[k][2] = A.z; v[k][3] = A.w;
                v[k][4] = Bv.x; v[k][5] = Bv.y; v[k][6] = Bv.z; v[k][7] = Bv.w;
            }

            float hh1[7], hh2[7], DRv[5], DLv[5], Vv[4];
#pragma unroll
            for (int k = 0; k < 7; ++k) {
                hh1[k] = __builtin_fabsf(v[1][k + 1] - v[1][k]);
                hh2[k] = __builtin_fabsf(v[2][k + 1] - v[2][k]);
            }
#pragma unroll
            for (int k = 0; k < 5; ++k) {
                DRv[k] = __builtin_fabsf(v[1][k + 1] - v[2][k]);
                DLv[k] = __builtin_fabsf(v[1][k] - v[2][k + 1]);
            }
#pragma unroll
            for (int k = 0; k < 4; ++k)
                Vv[k] = __builtin_fabsf(v[1][k + 1] - v[2][k + 1]);

            // offset order: (0,0),(0,1),(0,2),(1,0),(1,2),(2,0),(2,1),(2,2)
#pragma unroll
            for (int q = 0; q < 4; ++q) {
                float c1 = v[1][q + 1], c2 = v[2][q + 1];
                acc0[0][q] += __builtin_fabsf(c1 - v[0][q]);
                acc0[1][q] += __builtin_fabsf(c1 - v[0][q + 1]);
                acc0[2][q] += __builtin_fabsf(c1 - v[0][q + 2]);
                acc0[3][q] += hh1[q];
                acc0[4][q] += hh1[q + 1];
                acc0[5][q] += DRv[q];
                acc0[6][q] += Vv[q];
                acc0[7][q] += DLv[q + 1];

                acc1[0][q] += DLv[q];
                acc1[1][q] += Vv[q];
                acc1[2][q] += DRv[q + 1];
                acc1[3][q] += hh2[q];
                acc1[4][q] += hh2[q + 1];
                acc1[5][q] += __builtin_fabsf(c2 - v[3][q]);
                acc1[6][q] += __builtin_fabsf(c2 - v[3][q + 1]);
                acc1[7][q] += __builtin_fabsf(c2 - v[3][q + 2]);
            }
        }
        __syncthreads();  // drains vmcnt (staged c+1 ready) + protects buffers
    }

    if (lane < 56) {
        int r0 = i0 + rb;
#pragma unroll
        for (int dr = 0; dr < 2; ++dr) {
            int r = r0 + dr;
            if (r < HO) {
                float (*A)[4] = dr ? acc1 : acc0;   // folds after unroll
                float* obase = out + (size_t)batch * 8 * OPLANE + (size_t)r * WO + cg;
#pragma unroll
                for (int o = 0; o < 8; ++o) {
                    float* op = obase + (size_t)o * OPLANE;
                    *(float2*)op = make_float2(-A[o][0], -A[o][1]);
                    if (g < 55)
                        *(float2*)(op + 2) = make_float2(-A[o][2], -A[o][3]);
                }
            }
        }
    }
}

extern "C" void kernel_launch(void* const* d_in, const int* in_sizes, int n_in,
                              void* d_out, int out_size, void* d_ws, size_t ws_size,
                              hipStream_t stream) {
    const float* x = (const float*)d_in[0];
    float* out = (float*)d_out;
    nfp_sad_kernel<<<NBLK, 128, 0, stream>>>(x, out);
}

// Round 7
// 88.557 us; speedup vs baseline: 1.2094x; 1.2094x over previous
//
#include <hip/hip_runtime.h>
#include <stdint.h>

// NFP pooling: out[b,o,i,j] = -sum_c |x[b,c,i+1,j+1] - x[b,c,i+di,j+dj]|
// x: (8,128,224,224) f32 -> out: (8,8,222,222) f32.
//
// R7: R6 structure with the o4/hh bug fixed (mm now 6-wide; offset (1,2)
// at q=3 needs middle-row col 4l+5). Block = 1 output row x 8 channel
// chunks (16 ch/wave); lane l<56 owns cols 4l..4l+3. Per channel: 3
// coalesced float4 row loads (misses) + 3 overlapping +4 loads (L1 hits).
// Pure-register 2-stage pipeline, no barriers in loop; one syncthreads,
// 8-way LDS reduce, wave w stores offset plane w.

constexpr int C = 128;
constexpr int H = 224;
constexpr int W = 224;
constexpr int HO = 222;
constexpr int WO = 222;
constexpr int PLANE = H * W;              // 50176
constexpr int OPLANE = HO * WO;           // 49284
constexpr int CHW = 16;                   // channels per wave
constexpr int NBLK = 8 * HO;              // 1776 blocks

#define LOADCH(S, p)                                                   \
    S##t  = *reinterpret_cast<const float4*>(p);                       \
    S##tn = *reinterpret_cast<const float4*>((p) + nb);                \
    S##m  = *reinterpret_cast<const float4*>((p) + W);                 \
    S##mn = *reinterpret_cast<const float4*>((p) + W + nb);            \
    S##b  = *reinterpret_cast<const float4*>((p) + 2 * W);             \
    S##bn = *reinterpret_cast<const float4*>((p) + 2 * W + nb);

// offset order: (0,0),(0,1),(0,2),(1,0),(1,2),(2,0),(2,1),(2,2)
// output col q (global 4l+q): center = mm[q+1]; o3 -> hh[q], o4 -> hh[q+1]
#define COMPCH(S) {                                                    \
    float tt[6] = {S##t.x, S##t.y, S##t.z, S##t.w, S##tn.x, S##tn.y};  \
    float mm[6] = {S##m.x, S##m.y, S##m.z, S##m.w, S##mn.x, S##mn.y};  \
    float bb[6] = {S##b.x, S##b.y, S##b.z, S##b.w, S##bn.x, S##bn.y};  \
    float hh[5];                                                       \
    _Pragma("unroll")                                                  \
    for (int q = 0; q < 5; ++q) hh[q] = __builtin_fabsf(mm[q + 1] - mm[q]); \
    _Pragma("unroll")                                                  \
    for (int q = 0; q < 4; ++q) {                                      \
        float ctr = mm[q + 1];                                         \
        acc[0][q] += __builtin_fabsf(ctr - tt[q]);                     \
        acc[1][q] += __builtin_fabsf(ctr - tt[q + 1]);                 \
        acc[2][q] += __builtin_fabsf(ctr - tt[q + 2]);                 \
        acc[3][q] += hh[q];                                            \
        acc[4][q] += hh[q + 1];                                        \
        acc[5][q] += __builtin_fabsf(ctr - bb[q]);                     \
        acc[6][q] += __builtin_fabsf(ctr - bb[q + 1]);                 \
        acc[7][q] += __builtin_fabsf(ctr - bb[q + 2]);                 \
    }                                                                  \
}

__global__ __launch_bounds__(512, 4)
void nfp_sad_kernel(const float* __restrict__ x, float* __restrict__ out) {
    __shared__ float4 red[8][8][56];      // [offset][chunk][lane], 57,344 B

    int b = blockIdx.x / HO;
    int i = blockIdx.x % HO;              // output row; input rows i..i+2
    int w = threadIdx.x >> 6;             // wave = channel chunk 0..7
    int l = threadIdx.x & 63;             // lane; l<56 active, cols 4l..4l+3

    float acc[8][4];
#pragma unroll
    for (int o = 0; o < 8; ++o)
#pragma unroll
        for (int q = 0; q < 4; ++q) acc[o][q] = 0.0f;

    if (l < 56) {
        const float* p = x + (size_t)(b * C + w * CHW) * PLANE
                           + (size_t)i * W + 4 * l;
        // lane 55's +4 read would run past the plane end; its q=2,3 outputs
        // (cols 222,223) are never stored, so alias the neighbor load onto
        // its own float4 (values unused by valid outputs).
        const int nb = (l == 55) ? 0 : 4;

        float4 At, Atn, Am, Amn, Ab, Abn;
        float4 Bt, Btn, Bm, Bmn, Bb, Bbn;

        LOADCH(A, p); p += PLANE;                       // c0
        for (int k = 0; k < (CHW - 2) / 2; ++k) {       // 7 iters
            LOADCH(B, p); p += PLANE;                   // c 2k+1
            COMPCH(A);                                  // c 2k
            LOADCH(A, p); p += PLANE;                   // c 2k+2
            COMPCH(B);                                  // c 2k+1
        }
        LOADCH(B, p);                                   // c15
        COMPCH(A);                                      // c14
        COMPCH(B);                                      // c15

#pragma unroll
        for (int o = 0; o < 8; ++o)
            red[o][w][l] = make_float4(acc[o][0], acc[o][1], acc[o][2], acc[o][3]);
    }
    __syncthreads();

    // wave w reduces offset-plane w across the 8 chunks and stores its row
    if (l < 56) {
        float4 s = make_float4(0.f, 0.f, 0.f, 0.f);
#pragma unroll
        for (int c = 0; c < 8; ++c) {
            float4 v = red[w][c][l];
            s.x += v.x; s.y += v.y; s.z += v.z; s.w += v.w;
        }
        float* op = out + ((size_t)b * 8 + w) * OPLANE + (size_t)i * WO + 4 * l;
        *reinterpret_cast<float2*>(op) = make_float2(-s.x, -s.y);
        if (l < 55)   // col 4l+2 < 222
            *reinterpret_cast<float2*>(op + 2) = make_float2(-s.z, -s.w);
    }
}

extern "C" void kernel_launch(void* const* d_in, const int* in_sizes, int n_in,
                              void* d_out, int out_size, void* d_ws, size_t ws_size,
                              hipStream_t stream) {
    const float* x = (const float*)d_in[0];
    float* out = (float*)d_out;
    nfp_sad_kernel<<<NBLK, 512, 0, stream>>>(x, out);
}

// Round 9
// 65.092 us; speedup vs baseline: 1.6453x; 1.3605x over previous
//
#include <hip/hip_runtime.h>
#include <stdint.h>

// NFP pooling: out[b,o,i,j] = -sum_c |x[b,c,i+1,j+1] - x[b,c,i+di,j+dj]|
// x: (8,128,224,224) f32 -> out: (8,8,222,222) f32.
//
// R9: R8 structure (row-pair threads, shared-diff COMP, 4-way channel
// split, barrier-free loop, end LDS combine) with the macro token-paste
// bug replaced by inline functions. Traffic 616->410 MB via row-pair
// amortization; load instrs 2.37M->909k.

constexpr int C = 128;
constexpr int H = 224;
constexpr int W = 224;
constexpr int HO = 222;
constexpr int WO = 222;
constexpr int PLANE = H * W;              // 50176
constexpr int OPLANE = HO * WO;           // 49284
constexpr int RP = HO / 2;                // 111 row-pairs (exact)
constexpr int NBLK = 8 * RP;              // 888 blocks
constexpr int CHW = 32;                   // channels per wave (4 chunks)

struct ChRegs { float4 r0a, r0b, r1a, r1b, r2a, r2b, r3a, r3b; };

__device__ __forceinline__ void loadch(ChRegs& S, const float* p, int nb) {
    S.r0a = *reinterpret_cast<const float4*>(p);
    S.r0b = *reinterpret_cast<const float4*>(p + nb);
    S.r1a = *reinterpret_cast<const float4*>(p + W);
    S.r1b = *reinterpret_cast<const float4*>(p + W + nb);
    S.r2a = *reinterpret_cast<const float4*>(p + 2 * W);
    S.r2b = *reinterpret_cast<const float4*>(p + 2 * W + nb);
    S.r3a = *reinterpret_cast<const float4*>(p + 3 * W);
    S.r3b = *reinterpret_cast<const float4*>(p + 3 * W + nb);
}

// offset order: (0,0),(0,1),(0,2),(1,0),(1,2),(2,0),(2,1),(2,2)
// acc0: output row 2rp (center row v1); acc1: row 2rp+1 (center v2).
__device__ __forceinline__ void compch(const ChRegs& S,
                                       float (&acc0)[8][4], float (&acc1)[8][4]) {
    float v0[8] = {S.r0a.x, S.r0a.y, S.r0a.z, S.r0a.w, S.r0b.x, S.r0b.y, S.r0b.z, S.r0b.w};
    float v1[8] = {S.r1a.x, S.r1a.y, S.r1a.z, S.r1a.w, S.r1b.x, S.r1b.y, S.r1b.z, S.r1b.w};
    float v2[8] = {S.r2a.x, S.r2a.y, S.r2a.z, S.r2a.w, S.r2b.x, S.r2b.y, S.r2b.z, S.r2b.w};
    float v3[8] = {S.r3a.x, S.r3a.y, S.r3a.z, S.r3a.w, S.r3b.x, S.r3b.y, S.r3b.z, S.r3b.w};
    float hh1[5], hh2[5], DR[5], DL[5], Vv[5];
#pragma unroll
    for (int k = 0; k < 5; ++k) {
        hh1[k] = __builtin_fabsf(v1[k + 1] - v1[k]);
        hh2[k] = __builtin_fabsf(v2[k + 1] - v2[k]);
        DR[k]  = __builtin_fabsf(v1[k + 1] - v2[k]);
        DL[k]  = __builtin_fabsf(v1[k] - v2[k + 1]);
        Vv[k]  = __builtin_fabsf(v1[k + 1] - v2[k + 1]);
    }
#pragma unroll
    for (int q = 0; q < 4; ++q) {
        float c1 = v1[q + 1], c2 = v2[q + 1];
        acc0[0][q] += __builtin_fabsf(c1 - v0[q]);
        acc0[1][q] += __builtin_fabsf(c1 - v0[q + 1]);
        acc0[2][q] += __builtin_fabsf(c1 - v0[q + 2]);
        acc0[3][q] += hh1[q];
        acc0[4][q] += hh1[q + 1];
        acc0[5][q] += DR[q];
        acc0[6][q] += Vv[q];
        acc0[7][q] += DL[q + 1];
        acc1[0][q] += DL[q];
        acc1[1][q] += Vv[q];
        acc1[2][q] += DR[q + 1];
        acc1[3][q] += hh2[q];
        acc1[4][q] += hh2[q + 1];
        acc1[5][q] += __builtin_fabsf(c2 - v3[q]);
        acc1[6][q] += __builtin_fabsf(c2 - v3[q + 1]);
        acc1[7][q] += __builtin_fabsf(c2 - v3[q + 2]);
    }
}

__global__ __launch_bounds__(256, 1)
void nfp_sad_kernel(const float* __restrict__ x, float* __restrict__ out) {
    __shared__ float red[3][64][65];      // [chunk-1][lane][65], 49,920 B

    int b  = blockIdx.x / RP;
    int rp = blockIdx.x % RP;             // output rows 2rp, 2rp+1
    int w = threadIdx.x >> 6;             // wave = channel chunk 0..3
    int l = threadIdx.x & 63;             // lane; l<56 active, cols 4l..4l+3

    float acc0[8][4], acc1[8][4];
#pragma unroll
    for (int o = 0; o < 8; ++o)
#pragma unroll
        for (int q = 0; q < 4; ++q) { acc0[o][q] = 0.0f; acc1[o][q] = 0.0f; }

    if (l < 56) {
        // input rows 2rp..2rp+3 (max 223), cols 4l..4l+7 (max 223)
        const float* p = x + (size_t)(b * C + w * CHW) * PLANE
                           + (size_t)(2 * rp) * W + 4 * l;
        // lane 55: +4 reads would cross the row end; its q=2,3 outputs
        // (cols 222,223) are never stored, so alias onto its own float4.
        const int nb = (l == 55) ? 0 : 4;

        ChRegs A, B;
        loadch(A, p, nb); p += PLANE;                   // c0
        for (int k = 0; k < (CHW - 2) / 2; ++k) {       // 15 iters
            loadch(B, p, nb); p += PLANE;               // c 2k+1
            compch(A, acc0, acc1);                      // c 2k
            loadch(A, p, nb); p += PLANE;               // c 2k+2
            compch(B, acc0, acc1);                      // c 2k+1
        }
        loadch(B, p, nb);                               // c31
        compch(A, acc0, acc1);                          // c30
        compch(B, acc0, acc1);                          // c31

        if (w != 0) {
#pragma unroll
            for (int o = 0; o < 8; ++o)
#pragma unroll
                for (int q = 0; q < 4; ++q) {
                    red[w - 1][l][o * 4 + q]      = acc0[o][q];
                    red[w - 1][l][32 + o * 4 + q] = acc1[o][q];
                }
        }
    }
    __syncthreads();

    if (w == 0 && l < 56) {
#pragma unroll
        for (int o = 0; o < 8; ++o)
#pragma unroll
            for (int q = 0; q < 4; ++q) {
                acc0[o][q] += red[0][l][o * 4 + q] + red[1][l][o * 4 + q]
                            + red[2][l][o * 4 + q];
                acc1[o][q] += red[0][l][32 + o * 4 + q] + red[1][l][32 + o * 4 + q]
                            + red[2][l][32 + o * 4 + q];
            }

        float* ob = out + (size_t)b * 8 * OPLANE + (size_t)(2 * rp) * WO + 4 * l;
#pragma unroll
        for (int o = 0; o < 8; ++o) {
            float* op0 = ob + (size_t)o * OPLANE;       // row 2rp
            float* op1 = op0 + WO;                      // row 2rp+1
            *reinterpret_cast<float2*>(op0) = make_float2(-acc0[o][0], -acc0[o][1]);
            *reinterpret_cast<float2*>(op1) = make_float2(-acc1[o][0], -acc1[o][1]);
            if (l < 55) {   // cols 4l+2,4l+3 < 222
                *reinterpret_cast<float2*>(op0 + 2) = make_float2(-acc0[o][2], -acc0[o][3]);
                *reinterpret_cast<float2*>(op1 + 2) = make_float2(-acc1[o][2], -acc1[o][3]);
            }
        }
    }
}

extern "C" void kernel_launch(void* const* d_in, const int* in_sizes, int n_in,
                              void* d_out, int out_size, void* d_ws, size_t ws_size,
                              hipStream_t stream) {
    const float* x = (const float*)d_in[0];
    float* out = (float*)d_out;
    nfp_sad_kernel<<<NBLK, 256, 0, stream>>>(x, out);
}

// Round 10
// 53.029 us; speedup vs baseline: 2.0196x; 1.2275x over previous
//
#include <hip/hip_runtime.h>
#include <stdint.h>

// NFP pooling: out[b,o,i,j] = -sum_c |x[b,c,i+1,j+1] - x[b,c,i+di,j+dj]|
// x: (8,128,224,224) f32 -> out: (8,8,222,222) f32.
//
// R10: LDS-staged, fabric-traffic attack. Block = 4 output rows x 222 cols;
// 32 rounds of KC=4 channels: stage 4 planes' 6-row strips (21.5 KB) via
// global_load_lds w16, double-buffered, ONE barrier per round. Thread =
// 2col x 2row (R9's verified comp). XCD pinning: 448 blocks = 8 batches x
// 56 tiles, bid%8 = batch -> each batch resident on one XCD; per-round
// XCD working set ~3.6 MB fits the 4 MB L2 so row-halo re-reads hit L2.

constexpr int C = 128;
constexpr int H = 224;
constexpr int W = 224;
constexpr int HO = 222;
constexpr int WO = 222;
constexpr int PLANE = H * W;              // 50176
constexpr int OPLANE = HO * WO;           // 49284
constexpr int KC = 4;                     // channels per round
constexpr int ROUNDS = C / KC;            // 32
constexpr int TROWS = 4;                  // output rows per tile
constexpr int SROWS = 6;                  // staged input rows
constexpr int NT = 56;                    // row tiles per batch (56*4=224>=222)
constexpr int NBLK = 8 * NT;              // 448
constexpr int SLOTS = KC * SROWS * (W / 4);   // 1344 16-B slots per buffer

__device__ __forceinline__ void gload16(const float* g, float* l) {
    __builtin_amdgcn_global_load_lds(
        (const __attribute__((address_space(1))) void*)g,
        (__attribute__((address_space(3))) void*)l, 16, 0, 0);
}

__global__ __launch_bounds__(256, 1)
void nfp_sad_kernel(const float* __restrict__ x, float* __restrict__ out) {
    __shared__ float lds[2][SLOTS * 4];   // 2 x 21,504 B = 43,008 B

    int bid = blockIdx.x;
    int b = bid & 7;                      // batch == XCD (448 = 8*56, bijective)
    int t = bid >> 3;                     // row tile 0..55
    int i0 = t * TROWS;                   // first output row; staged rows i0..i0+5
    int tid = threadIdx.x;

    // --- staging slot precompute: slot v = j*256 + tid, v < 1344 ---
    // v -> c = v/336, r = (v%336)/56, k = v%56 ; global row clamped to 223
    const float* xb = x + (size_t)b * C * PLANE;
    int goff[6];
#pragma unroll
    for (int j = 0; j < 6; ++j) {
        int v = j * 256 + tid;
        int vv = v < SLOTS ? v : SLOTS - 1;
        int c = vv / 336, rem = vv % 336;
        int r = rem / 56, k = rem % 56;
        int row = i0 + r; if (row > H - 1) row = H - 1;
        goff[j] = c * PLANE + row * W + k * 4;
    }

    // --- compute-role decode: slot s = tid (<222), rp = s/111, cp = s%111 ---
    int s = tid;
    bool act = s < 222;
    int rp = act ? (s / 111) : 0;         // rowpair within tile
    int cp = act ? (s % 111) : 0;         // colpair: output cols 2cp, 2cp+1

    float acc0[8][2], acc1[8][2];
#pragma unroll
    for (int o = 0; o < 8; ++o) {
        acc0[o][0] = acc0[o][1] = 0.0f;
        acc1[o][0] = acc1[o][1] = 0.0f;
    }

    // stage round 0
    {
        float* dst = &lds[0][0];
#pragma unroll
        for (int j = 0; j < 5; ++j)
            gload16(xb + goff[j], dst + (j * 256 + tid) * 4);
        if (tid < 64) gload16(xb + goff[5], dst + (5 * 256 + tid) * 4);
    }

    int choff = 0;                        // channel offset (floats)
    for (int rd = 0; rd < ROUNDS; ++rd) {
        __syncthreads();                  // stage(rd) complete (drains vmcnt)

        if (rd + 1 < ROUNDS) {            // issue DMA for next round
            int noff = choff + KC * PLANE;
            float* dst = &lds[(rd + 1) & 1][0];
#pragma unroll
            for (int j = 0; j < 5; ++j)
                gload16(xb + noff + goff[j], dst + (j * 256 + tid) * 4);
            if (tid < 64) gload16(xb + noff + goff[5], dst + (5 * 256 + tid) * 4);
        }

        if (act) {
            const float* Bf = &lds[rd & 1][0];
#pragma unroll
            for (int c = 0; c < KC; ++c) {
                // staged rows 2rp..2rp+3, cols 2cp..2cp+3 (4 floats/row)
                const float* pc = Bf + (c * SROWS + 2 * rp) * W + 2 * cp;
                float v0[4], v1[4], v2[4], v3[4];
                *(float2*)&v0[0] = *(const float2*)(pc);
                *(float2*)&v0[2] = *(const float2*)(pc + 2);
                *(float2*)&v1[0] = *(const float2*)(pc + W);
                *(float2*)&v1[2] = *(const float2*)(pc + W + 2);
                *(float2*)&v2[0] = *(const float2*)(pc + 2 * W);
                *(float2*)&v2[2] = *(const float2*)(pc + 2 * W + 2);
                *(float2*)&v3[0] = *(const float2*)(pc + 3 * W);
                *(float2*)&v3[2] = *(const float2*)(pc + 3 * W + 2);

                float hh1[3], hh2[3], DR[3], DL[3], Vv[2];
#pragma unroll
                for (int k = 0; k < 3; ++k) {
                    hh1[k] = __builtin_fabsf(v1[k + 1] - v1[k]);
                    hh2[k] = __builtin_fabsf(v2[k + 1] - v2[k]);
                    DR[k]  = __builtin_fabsf(v1[k + 1] - v2[k]);
                    DL[k]  = __builtin_fabsf(v1[k] - v2[k + 1]);
                }
                Vv[0] = __builtin_fabsf(v1[1] - v2[1]);
                Vv[1] = __builtin_fabsf(v1[2] - v2[2]);

                // offset order: (0,0),(0,1),(0,2),(1,0),(1,2),(2,0),(2,1),(2,2)
#pragma unroll
                for (int q = 0; q < 2; ++q) {
                    float c1 = v1[q + 1], c2 = v2[q + 1];
                    acc0[0][q] += __builtin_fabsf(c1 - v0[q]);
                    acc0[1][q] += __builtin_fabsf(c1 - v0[q + 1]);
                    acc0[2][q] += __builtin_fabsf(c1 - v0[q + 2]);
                    acc0[3][q] += hh1[q];
                    acc0[4][q] += hh1[q + 1];
                    acc0[5][q] += DR[q];
                    acc0[6][q] += Vv[q];
                    acc0[7][q] += DL[q + 1];
                    acc1[0][q] += DL[q];
                    acc1[1][q] += Vv[q];
                    acc1[2][q] += DR[q + 1];
                    acc1[3][q] += hh2[q];
                    acc1[4][q] += hh2[q + 1];
                    acc1[5][q] += __builtin_fabsf(c2 - v3[q]);
                    acc1[6][q] += __builtin_fabsf(c2 - v3[q + 1]);
                    acc1[7][q] += __builtin_fabsf(c2 - v3[q + 2]);
                }
            }
        }
        choff += KC * PLANE;
    }

    if (act) {
        int r0 = i0 + 2 * rp;             // first of this thread's 2 output rows
        float* ob = out + (size_t)b * 8 * OPLANE + 2 * cp;
#pragma unroll
        for (int o = 0; o < 8; ++o) {
            float* op = ob + (size_t)o * OPLANE;
            if (r0 < HO)
                *(float2*)(op + (size_t)r0 * WO) = make_float2(-acc0[o][0], -acc0[o][1]);
            if (r0 + 1 < HO)
                *(float2*)(op + (size_t)(r0 + 1) * WO) = make_float2(-acc1[o][0], -acc1[o][1]);
        }
    }
}

extern "C" void kernel_launch(void* const* d_in, const int* in_sizes, int n_in,
                              void* d_out, int out_size, void* d_ws, size_t ws_size,
                              hipStream_t stream) {
    const float* x = (const float*)d_in[0];
    float* out = (float*)d_out;
    nfp_sad_kernel<<<NBLK, 256, 0, stream>>>(x, out);
}